// Round 1
// 212.499 us; speedup vs baseline: 1.0359x; 1.0359x over previous
//
#include <hip/hip_runtime.h>
#include <math.h>
#include <stdint.h>

// ContentAttention fused, round 4.
// convert_k: K fp32 -> ws as PLAIN [col][k] bf16 hi/lo planes (32KB each) —
//   layout chosen so one global_load_dwordx4 per lane IS an MFMA B-fragment.
// attn_fused_v4: 8 waves (512 thr), wave tile 64x64 (acc[4][4]).
//   B: L2 -> VGPR direct, double-buffered in registers (pbA/pbB, static
//      indexing), prefetch 1 k-tile ahead, compiler-counted vmcnt (no drain).
//   A: only operand in LDS (8KB/ktile, rotated conflict-free image, dbuf).
//   Barrier per k-tile is raw s_barrier + lgkmcnt(0) ONLY — B loads stay in
//   flight across it (v3's __syncthreads drained vmcnt(0) every tile and the
//   16-wave lockstep put 192 ds_read_b128 + 64KB DMA on the LDS pipe per
//   tile: ~2900cy vs MFMA 1546cy/SIMD; v4 cuts LDS to 64 reads ≈ 768cy).
// Fallback v1 kept for ws_size < WS_TOTAL.

#define NB 32
#define NQ 512
#define NK 512
#define ND 1024
#define BK 32
#define NT (ND / BK)            // 32 k-tiles
#define BM1 64                  // fallback rows/block
#define BM4 64                  // v4 rows/block
#define TILE_BYTES 65536        // per (batch,kt): 32KB hi + 32KB lo
#define WS_TILES ((size_t)NB * NT * TILE_BYTES)        // 64 MiB
#define WS_TOTAL (WS_TILES + (size_t)NB * NK * 4)      // + mask 64 KiB

typedef __attribute__((ext_vector_type(8))) short short8;
typedef __attribute__((ext_vector_type(4))) float f32x4;

__device__ __forceinline__ void bf_split(float x, unsigned& hbits, float& lo) {
  unsigned u = __float_as_uint(x);
  unsigned r = u + 0x7fffu + ((u >> 16) & 1u);
  hbits = r & 0xffff0000u;
  lo = x - __uint_as_float(hbits);
}
__device__ __forceinline__ unsigned pack_rn(float x0, float x1) {
  unsigned u0 = __float_as_uint(x0), u1 = __float_as_uint(x1);
  unsigned r0 = u0 + 0x7fffu + ((u0 >> 16) & 1u);
  unsigned r1 = u1 + 0x7fffu + ((u1 >> 16) & 1u);
  return (r0 >> 16) | (r1 & 0xffff0000u);
}

// Rotated LDS image for the A tile (and v1): 64B rows, 16B chunk slot rotated
// by row>>1. 2-way everywhere (free, m136); measured 0 bank conflicts.
__device__ __forceinline__ int lds_off_write(int r, int c4) {
  int slot = ((c4 >> 1) + (r >> 1)) & 3;
  return r * 32 + slot * 8 + (c4 & 1) * 4;   // ushort units
}
__device__ __forceinline__ int lds_off_read(int r, int quad) {
  int slot = (quad + (r >> 1)) & 3;
  return r * 32 + slot * 8;                  // ushort units (16B frag)
}

// ---------------------------------------------------------------------------
// Kernel 1: K fp32 -> ws plain [col][k] bf16 hi/lo planes + mask floats
// ---------------------------------------------------------------------------
__global__ __launch_bounds__(256)
void convert_k(const float* __restrict__ Kg, unsigned char* __restrict__ ws) {
  const int bx = blockIdx.x;          // 0..1023
  const int batch = bx >> 5, kt = bx & 31;
  const float* src = Kg + (size_t)batch * NK * ND + kt * BK;
  unsigned short* hiB = (unsigned short*)(ws + (size_t)bx * TILE_BYTES);
  unsigned short* loB = hiB + 32768 / 2;
  float* maskB = (float*)(ws + WS_TILES) + batch * NK;

#pragma unroll
  for (int i = 0; i < 16; ++i) {
    int idx = threadIdx.x + 256 * i;
    int c = idx >> 3, c4 = idx & 7;     // c: key col 0..511, c4: k-group of 4
    float4 v = *(const float4*)(src + (size_t)c * ND + c4 * 4);
    unsigned h0, h1, h2, h3;
    float l0, l1, l2, l3;
    bf_split(v.x, h0, l0); bf_split(v.y, h1, l1);
    bf_split(v.z, h2, l2); bf_split(v.w, h3, l3);
    int off = c * 32 + c4 * 4;          // plain [col][k], 64B per col
    *(uint2*)(&hiB[off]) = make_uint2((h0 >> 16) | h1, (h2 >> 16) | h3);
    *(uint2*)(&loB[off]) = make_uint2(pack_rn(l0, l1), pack_rn(l2, l3));
    if (kt == 0 && c4 == 0) maskB[c] = v.x;
  }
}

// ---------------------------------------------------------------------------
// A staging: fp32 float4 -> rotated hi/lo bf16 LDS image
// ---------------------------------------------------------------------------
__device__ __forceinline__ void stage_a(unsigned short* hiA, unsigned short* loA,
                                        int ar, int ac4, float4 v) {
  unsigned h0, h1, h2, h3;
  float l0, l1, l2, l3;
  bf_split(v.x, h0, l0); bf_split(v.y, h1, l1);
  bf_split(v.z, h2, l2); bf_split(v.w, h3, l3);
  int off = lds_off_write(ar, ac4);
  *(uint2*)(&hiA[off]) = make_uint2((h0 >> 16) | h1, (h2 >> 16) | h3);
  *(uint2*)(&loA[off]) = make_uint2(pack_rn(l0, l1), pack_rn(l2, l3));
}

#define MFMA_BF16 __builtin_amdgcn_mfma_f32_16x16x32_bf16

// One k-tile: read A frags (LDS cur), issue next B loads + stage next A,
// 48 MFMAs on register-resident B, then lgkm-only barrier (vmem uncounted —
// B prefetch stays in flight across it; compiler emits counted vmcnt before
// the next body's first MFMA use of NXTB).
#define BODY(KT, CURB, NXTB, CUR, NXT)                                         \
  do {                                                                         \
    short8 ahi[4], alo[4];                                                     \
    _Pragma("unroll") for (int mt = 0; mt < 4; ++mt) {                         \
      int off = lds_off_read(mt * 16 + ln15, quad);                            \
      ahi[mt] = *(const short8*)(&sAhi[CUR][off]);                             \
      alo[mt] = *(const short8*)(&sAlo[CUR][off]);                             \
    }                                                                          \
    if ((KT) + 1 < NT) {                                                       \
      const unsigned char* tb = wsB + (size_t)((KT) + 1) * TILE_BYTES;         \
      _Pragma("unroll") for (int nt = 0; nt < 4; ++nt) {                       \
        NXTB[2 * nt]     = *(const float4*)(tb + nt * 1024 + boff);            \
        NXTB[2 * nt + 1] = *(const float4*)(tb + 32768 + nt * 1024 + boff);    \
      }                                                                        \
      stage_a(sAhi[NXT], sAlo[NXT], ar, ac4, pa);                              \
      if ((KT) + 2 < NT)                                                       \
        pa = *(const float4*)(Qp + ((KT) + 2) * BK + (size_t)ar * ND + ac4 * 4);\
    }                                                                          \
    _Pragma("unroll") for (int nt = 0; nt < 4; ++nt) {                         \
      short8 bhi = *(const short8*)(&CURB[2 * nt]);                            \
      short8 blo = *(const short8*)(&CURB[2 * nt + 1]);                        \
      _Pragma("unroll") for (int mt = 0; mt < 4; ++mt) {                       \
        acc[mt][nt] = MFMA_BF16(ahi[mt], bhi, acc[mt][nt], 0, 0, 0);           \
        acc[mt][nt] = MFMA_BF16(ahi[mt], blo, acc[mt][nt], 0, 0, 0);           \
        acc[mt][nt] = MFMA_BF16(alo[mt], bhi, acc[mt][nt], 0, 0, 0);           \
      }                                                                        \
    }                                                                          \
    asm volatile("s_waitcnt lgkmcnt(0)" ::: "memory");                         \
    __builtin_amdgcn_s_barrier();                                              \
  } while (0)

// ---------------------------------------------------------------------------
// Kernel 2 (v4): 512 threads, 8 waves x (64 rows x 64 cols), B in registers
// ---------------------------------------------------------------------------
__global__ __launch_bounds__(512, 2)
void attn_fused_v4(const float* __restrict__ Qg,
                   const unsigned char* __restrict__ ws,
                   const float* __restrict__ Tp, const float* __restrict__ Bp,
                   float* __restrict__ attn, float* __restrict__ conf) {
  __shared__ __align__(16) unsigned short sAhi[2][BM4 * BK];  // 2 x 4 KB
  __shared__ __align__(16) unsigned short sAlo[2][BM4 * BK];  // 2 x 4 KB
  __shared__ __align__(16) float sRedA[BM4][8];               // 2 KB
  __shared__ __align__(16) float sRedB[BM4][8];               // 2 KB

  const int tid = threadIdx.x;
  const int g = blockIdx.x;                       // 0..255
  const int batch = (g & 7) | (((g >> 3) & 3) << 3);   // co-XCD per batch
  const int q0 = (g >> 5) * BM4;                  // 8 q-chunks of 64
  const int ln = tid & 63, w = tid >> 6;          // w: 0..7 (one col-group each)
  const int ln15 = ln & 15, quad = ln >> 4;
  const int col0 = w * 64;

  const float* Qp = Qg + ((size_t)batch * NQ + q0) * ND;
  const unsigned char* wsB = ws + (size_t)batch * NT * TILE_BYTES;
  const float* maskB = (const float*)(ws + WS_TILES) + batch * NK;

  // Per-lane B offset: lane(ln) reads col=col0+(ln&15), k-chunk=(ln>>4) —
  // the 64 lanes of a wave cover one contiguous 1KB segment per (nt,plane).
  const int boff = (col0 << 6) + (ln15 << 6) + (quad << 4);
  const int ar = tid >> 3, ac4 = tid & 7;         // 64 rows x 8 float4 (all thr)

  f32x4 acc[4][4];
#pragma unroll
  for (int mt = 0; mt < 4; ++mt)
#pragma unroll
    for (int nt = 0; nt < 4; ++nt) acc[mt][nt] = (f32x4){0.f, 0.f, 0.f, 0.f};

  // ---- prologue: stage A(0), prefetch A(1), load B(0) into regs ----
  float4 a0 = *(const float4*)(Qp + (size_t)ar * ND + ac4 * 4);
  stage_a(sAhi[0], sAlo[0], ar, ac4, a0);
  float4 pa = *(const float4*)(Qp + BK + (size_t)ar * ND + ac4 * 4);
  float4 pbA[8], pbB[8];
#pragma unroll
  for (int nt = 0; nt < 4; ++nt) {
    pbA[2 * nt]     = *(const float4*)(wsB + nt * 1024 + boff);
    pbA[2 * nt + 1] = *(const float4*)(wsB + 32768 + nt * 1024 + boff);
  }
  asm volatile("s_waitcnt lgkmcnt(0)" ::: "memory");
  __builtin_amdgcn_s_barrier();

  for (int kt = 0; kt < NT; kt += 2) {
    BODY(kt, pbA, pbB, 0, 1);
    BODY(kt + 1, pbB, pbA, 1, 0);
  }

  // ============== epilogue: mask + softmax + confidence ==============
  const float NEGINF = -__builtin_inff();
  float rm[4][4];
#pragma unroll
  for (int mt = 0; mt < 4; ++mt)
#pragma unroll
    for (int rg = 0; rg < 4; ++rg) rm[mt][rg] = NEGINF;

#pragma unroll
  for (int nt = 0; nt < 4; ++nt) {
    int col = col0 + nt * 16 + ln15;
    bool msk = (maskB[col] == 0.0f);
#pragma unroll
    for (int mt = 0; mt < 4; ++mt)
#pragma unroll
      for (int rg = 0; rg < 4; ++rg) {
        float v = msk ? NEGINF : acc[mt][nt][rg];
        acc[mt][nt][rg] = v;
        rm[mt][rg] = fmaxf(rm[mt][rg], v);
      }
  }
#pragma unroll
  for (int mt = 0; mt < 4; ++mt)
#pragma unroll
    for (int rg = 0; rg < 4; ++rg) {
      float v = rm[mt][rg];
#pragma unroll
      for (int d = 1; d < 16; d <<= 1) v = fmaxf(v, __shfl_xor(v, d, 64));
      rm[mt][rg] = v;
    }
  if (ln15 == 0) {
#pragma unroll
    for (int mt = 0; mt < 4; ++mt)
#pragma unroll
      for (int rg = 0; rg < 4; ++rg)
        sRedA[mt * 16 + quad * 4 + rg][w] = rm[mt][rg];
  }
  __syncthreads();

  float gmax[4][4], gsum[4][4];
#pragma unroll
  for (int mt = 0; mt < 4; ++mt)
#pragma unroll
    for (int rg = 0; rg < 4; ++rg) {
      int row = mt * 16 + quad * 4 + rg;
      f32x4 p0 = *(const f32x4*)(&sRedA[row][0]);
      f32x4 p1 = *(const f32x4*)(&sRedA[row][4]);
      gmax[mt][rg] = fmaxf(fmaxf(fmaxf(p0[0], p0[1]), fmaxf(p0[2], p0[3])),
                           fmaxf(fmaxf(p1[0], p1[1]), fmaxf(p1[2], p1[3])));
      gsum[mt][rg] = 0.f;
    }

#pragma unroll
  for (int nt = 0; nt < 4; ++nt)
#pragma unroll
    for (int mt = 0; mt < 4; ++mt)
#pragma unroll
      for (int rg = 0; rg < 4; ++rg) {
        float e = __expf(acc[mt][nt][rg] - gmax[mt][rg]);
        acc[mt][nt][rg] = e;
        gsum[mt][rg] += e;
      }
#pragma unroll
  for (int mt = 0; mt < 4; ++mt)
#pragma unroll
    for (int rg = 0; rg < 4; ++rg) {
      float v = gsum[mt][rg];
#pragma unroll
      for (int d = 1; d < 16; d <<= 1) v += __shfl_xor(v, d, 64);
      gsum[mt][rg] = v;
    }
  if (ln15 == 0) {
#pragma unroll
    for (int mt = 0; mt < 4; ++mt)
#pragma unroll
      for (int rg = 0; rg < 4; ++rg)
        sRedB[mt * 16 + quad * 4 + rg][w] = gsum[mt][rg];
  }
  __syncthreads();
#pragma unroll
  for (int mt = 0; mt < 4; ++mt)
#pragma unroll
    for (int rg = 0; rg < 4; ++rg) {
      int row = mt * 16 + quad * 4 + rg;
      f32x4 p0 = *(const f32x4*)(&sRedB[row][0]);
      f32x4 p1 = *(const f32x4*)(&sRedB[row][4]);
      gsum[mt][rg] = (p0[0] + p0[1]) + (p0[2] + p0[3]) +
                     ((p1[0] + p1[1]) + (p1[2] + p1[3]));
    }

  float* outBase = attn + ((size_t)batch * NQ + q0) * NK;
#pragma unroll
  for (int mt = 0; mt < 4; ++mt)
#pragma unroll
    for (int rg = 0; rg < 4; ++rg) {
      int row = mt * 16 + quad * 4 + rg;
      float inv = 1.0f / gsum[mt][rg];
#pragma unroll
      for (int nt = 0; nt < 4; ++nt)
        outBase[(size_t)row * NK + col0 + nt * 16 + ln15] = acc[mt][nt][rg] * inv;
    }

  if (w == 0 && ln15 == 0) {   // 4 lanes cover rows via quad x mt x rg
    float tv = Tp[0], bv = Bp[0];
#pragma unroll
    for (int mt = 0; mt < 4; ++mt)
#pragma unroll
      for (int rg = 0; rg < 4; ++rg) {
        int row = mt * 16 + quad * 4 + rg;
        float lse = gmax[mt][rg] + __logf(gsum[mt][rg]);
        float t = (lse + bv) * tv;
        conf[(size_t)batch * NQ + q0 + row] = 1.0f / (1.0f + __expf(-t));
      }
  }
}

// ---------------------------------------------------------------------------
// Fallback: R1 single-kernel path (used only if ws_size < WS_TOTAL)
// ---------------------------------------------------------------------------
__global__ __launch_bounds__(256, 1)
void attn_fused_v1(const float* __restrict__ Qg, const float* __restrict__ Kg,
                   const float* __restrict__ Tp, const float* __restrict__ Bp,
                   float* __restrict__ attn, float* __restrict__ conf) {
  __shared__ __align__(16) unsigned short sAhi[BM1 * BK];
  __shared__ __align__(16) unsigned short sAlo[BM1 * BK];
  __shared__ __align__(16) unsigned short sBhi[NK * BK];
  __shared__ __align__(16) unsigned short sBlo[NK * BK];
  __shared__ float sRedA[4][BM1];
  __shared__ float sRedB[4][BM1];

  const int tid = threadIdx.x;
  const int g = blockIdx.x;
  const int batch = (g & 7) | (((g >> 3) & 3) << 3);
  const int q0 = (g >> 5) * BM1;
  const int ln = tid & 63, w = tid >> 6;
  const int ln15 = ln & 15, quad = ln >> 4;
  const int wn0 = w * 128;

  const float* Qp = Qg + ((size_t)batch * NQ + q0) * ND;
  const float* Kp = Kg + (size_t)batch * NK * ND;

  f32x4 acc[4][8];
#pragma unroll
  for (int mt = 0; mt < 4; ++mt)
#pragma unroll
    for (int nt = 0; nt < 8; ++nt) acc[mt][nt] = (f32x4){0.f, 0.f, 0.f, 0.f};

  float4 pb[16], pa[2];
#pragma unroll
  for (int i = 0; i < 16; ++i) {
    int idx = tid + 256 * i, r = idx >> 3, c4 = idx & 7;
    pb[i] = *(const float4*)(Kp + (size_t)r * ND + c4 * 4);
  }
#pragma unroll
  for (int i = 0; i < 2; ++i) {
    int idx = tid + 256 * i, r = idx >> 3, c4 = idx & 7;
    pa[i] = *(const float4*)(Qp + (size_t)r * ND + c4 * 4);
  }

  for (int kt = 0; kt < NT; ++kt) {
    if (kt) __syncthreads();
#pragma unroll
    for (int i = 0; i < 2; ++i) {
      int idx = tid + 256 * i, r = idx >> 3, c4 = idx & 7;
      int off = lds_off_write(r, c4);
      unsigned h0, h1, h2, h3; float l0, l1, l2, l3;
      bf_split(pa[i].x, h0, l0); bf_split(pa[i].y, h1, l1);
      bf_split(pa[i].z, h2, l2); bf_split(pa[i].w, h3, l3);
      *(uint2*)(&sAhi[off]) = make_uint2((h0 >> 16) | h1, (h2 >> 16) | h3);
      *(uint2*)(&sAlo[off]) = make_uint2(pack_rn(l0, l1), pack_rn(l2, l3));
    }
#pragma unroll
    for (int i = 0; i < 16; ++i) {
      int idx = tid + 256 * i, r = idx >> 3, c4 = idx & 7;
      int off = lds_off_write(r, c4);
      unsigned h0, h1, h2, h3; float l0, l1, l2, l3;
      bf_split(pb[i].x, h0, l0); bf_split(pb[i].y, h1, l1);
      bf_split(pb[i].z, h2, l2); bf_split(pb[i].w, h3, l3);
      *(uint2*)(&sBhi[off]) = make_uint2((h0 >> 16) | h1, (h2 >> 16) | h3);
      *(uint2*)(&sBlo[off]) = make_uint2(pack_rn(l0, l1), pack_rn(l2, l3));
    }
    __syncthreads();

    if (kt < NT - 1) {
      const float* Kq = Kp + (kt + 1) * BK;
      const float* Qq = Qp + (kt + 1) * BK;
#pragma unroll
      for (int i = 0; i < 16; ++i) {
        int idx = tid + 256 * i, r = idx >> 3, c4 = idx & 7;
        pb[i] = *(const float4*)(Kq + (size_t)r * ND + c4 * 4);
      }
#pragma unroll
      for (int i = 0; i < 2; ++i) {
        int idx = tid + 256 * i, r = idx >> 3, c4 = idx & 7;
        pa[i] = *(const float4*)(Qq + (size_t)r * ND + c4 * 4);
      }
    }

    short8 ahi[4], alo[4];
#pragma unroll
    for (int mt = 0; mt < 4; ++mt) {
      int off = lds_off_read(mt * 16 + ln15, quad);
      ahi[mt] = *(const short8*)(&sAhi[off]);
      alo[mt] = *(const short8*)(&sAlo[off]);
    }
#pragma unroll
    for (int nt = 0; nt < 8; ++nt) {
      int off = lds_off_read(wn0 + nt * 16 + ln15, quad);
      short8 bhi = *(const short8*)(&sBhi[off]);
      short8 blo = *(const short8*)(&sBlo[off]);
#pragma unroll
      for (int mt = 0; mt < 4; ++mt) {
        acc[mt][nt] = MFMA_BF16(ahi[mt], bhi, acc[mt][nt], 0, 0, 0);
        acc[mt][nt] = MFMA_BF16(ahi[mt], blo, acc[mt][nt], 0, 0, 0);
        acc[mt][nt] = MFMA_BF16(alo[mt], bhi, acc[mt][nt], 0, 0, 0);
      }
    }
  }

  const float NEGINF = -__builtin_inff();
  float rm[4][4];
#pragma unroll
  for (int mt = 0; mt < 4; ++mt)
#pragma unroll
    for (int rg = 0; rg < 4; ++rg) rm[mt][rg] = NEGINF;
#pragma unroll
  for (int nt = 0; nt < 8; ++nt) {
    int col = wn0 + nt * 16 + ln15;
    bool msk = (Kp[(size_t)col * ND] == 0.0f);
#pragma unroll
    for (int mt = 0; mt < 4; ++mt)
#pragma unroll
      for (int rg = 0; rg < 4; ++rg) {
        float v = msk ? NEGINF : acc[mt][nt][rg];
        acc[mt][nt][rg] = v;
        rm[mt][rg] = fmaxf(rm[mt][rg], v);
      }
  }
#pragma unroll
  for (int mt = 0; mt < 4; ++mt)
#pragma unroll
    for (int rg = 0; rg < 4; ++rg) {
      float v = rm[mt][rg];
#pragma unroll
      for (int d = 1; d < 16; d <<= 1) v = fmaxf(v, __shfl_xor(v, d, 64));
      rm[mt][rg] = v;
    }
  if (ln15 == 0)
#pragma unroll
    for (int mt = 0; mt < 4; ++mt)
#pragma unroll
      for (int rg = 0; rg < 4; ++rg)
        sRedA[w][mt * 16 + quad * 4 + rg] = rm[mt][rg];
  __syncthreads();

  float gmax[4][4], gsum[4][4];
#pragma unroll
  for (int mt = 0; mt < 4; ++mt)
#pragma unroll
    for (int rg = 0; rg < 4; ++rg) {
      int row = mt * 16 + quad * 4 + rg;
      gmax[mt][rg] = fmaxf(fmaxf(sRedA[0][row], sRedA[1][row]),
                           fmaxf(sRedA[2][row], sRedA[3][row]));
      gsum[mt][rg] = 0.f;
    }
#pragma unroll
  for (int nt = 0; nt < 8; ++nt)
#pragma unroll
    for (int mt = 0; mt < 4; ++mt)
#pragma unroll
      for (int rg = 0; rg < 4; ++rg) {
        float e = __expf(acc[mt][nt][rg] - gmax[mt][rg]);
        acc[mt][nt][rg] = e;
        gsum[mt][rg] += e;
      }
#pragma unroll
  for (int mt = 0; mt < 4; ++mt)
#pragma unroll
    for (int rg = 0; rg < 4; ++rg) {
      float v = gsum[mt][rg];
#pragma unroll
      for (int d = 1; d < 16; d <<= 1) v += __shfl_xor(v, d, 64);
      gsum[mt][rg] = v;
    }
  if (ln15 == 0)
#pragma unroll
    for (int mt = 0; mt < 4; ++mt)
#pragma unroll
      for (int rg = 0; rg < 4; ++rg)
        sRedB[w][mt * 16 + quad * 4 + rg] = gsum[mt][rg];
  __syncthreads();
#pragma unroll
  for (int mt = 0; mt < 4; ++mt)
#pragma unroll
    for (int rg = 0; rg < 4; ++rg) {
      int row = mt * 16 + quad * 4 + rg;
      gsum[mt][rg] = sRedB[0][row] + sRedB[1][row] + sRedB[2][row] + sRedB[3][row];
    }

  float* outBase = attn + ((size_t)batch * NQ + q0) * NK;
#pragma unroll
  for (int mt = 0; mt < 4; ++mt)
#pragma unroll
    for (int rg = 0; rg < 4; ++rg) {
      int row = mt * 16 + quad * 4 + rg;
      float inv = 1.0f / gsum[mt][rg];
#pragma unroll
      for (int nt = 0; nt < 8; ++nt)
        outBase[(size_t)row * NK + wn0 + nt * 16 + ln15] = acc[mt][nt][rg] * inv;
    }
  if (w == 0 && ln15 == 0) {
    float tv = Tp[0], bv = Bp[0];
#pragma unroll
    for (int mt = 0; mt < 4; ++mt)
#pragma unroll
      for (int rg = 0; rg < 4; ++rg) {
        int row = mt * 16 + quad * 4 + rg;
        float lse = gmax[mt][rg] + __logf(gsum[mt][rg]);
        float t = (lse + bv) * tv;
        conf[(size_t)batch * NQ + q0 + row] = 1.0f / (1.0f + __expf(-t));
      }
  }
}

extern "C" void kernel_launch(void* const* d_in, const int* in_sizes, int n_in,
                              void* d_out, int out_size, void* d_ws, size_t ws_size,
                              hipStream_t stream) {
  const float* q = (const float*)d_in[0];
  const float* k = (const float*)d_in[1];
  const float* temp = (const float*)d_in[2];
  const float* bias = (const float*)d_in[3];
  float* attn = (float*)d_out;
  float* conf = attn + (size_t)NB * NQ * NK;

  if (ws_size >= WS_TOTAL) {
    hipLaunchKernelGGL(convert_k, dim3(NB * NT), dim3(256), 0, stream,
                       k, (unsigned char*)d_ws);
    hipLaunchKernelGGL(attn_fused_v4, dim3(NB * (NQ / BM4)), dim3(512), 0, stream,
                       q, (const unsigned char*)d_ws, temp, bias, attn, conf);
  } else {
    hipLaunchKernelGGL(attn_fused_v1, dim3(NB * (NQ / BM1)), dim3(256), 0, stream,
                       q, k, temp, bias, attn, conf);
  }
}